// Round 1
// baseline (557.197 us; speedup 1.0000x reference)
//
#include <hip/hip_runtime.h>

// AdditiveAttention on MI355X (gfx950)
// B=64, S=2048, D=512, U=512. All inputs fp32; output fp32 (B,D).
//
// Pipeline:
//  k1 qk        : Q = query@W1                       (fp32, tiny)
//  k2 wt_k      : Wt[u][d] = bf16(W2[d][u])          (transpose+convert for MFMA B-frags)
//  k3 scores_k  : score[b,s] = sum_u tanh(Q[b,u] + (values[b,s,:]@W2)[u]) * V1[u]
//                 bf16 MFMA 16x16x32, full-K A-tile in LDS, fused tanh/V1 epilogue
//  k4 softmax_k : scores <- softmax over S (in place)
//  k5 ctx_k     : out[b,d] = sum_s attn[b,s]*values[b,s,d]

typedef __attribute__((ext_vector_type(8))) short bf16x8;
typedef __attribute__((ext_vector_type(4))) float f32x4;

#if __has_builtin(__builtin_amdgcn_exp2f)
__device__ __forceinline__ float fast_exp2(float x) { return __builtin_amdgcn_exp2f(x); }
#else
__device__ __forceinline__ float fast_exp2(float x) { return exp2f(x); }
#endif
#if __has_builtin(__builtin_amdgcn_rcpf)
__device__ __forceinline__ float fast_rcp(float x) { return __builtin_amdgcn_rcpf(x); }
#else
__device__ __forceinline__ float fast_rcp(float x) { return 1.0f / x; }
#endif

__device__ __forceinline__ unsigned short f2bf(float f) {
  // round-to-nearest-even fp32 -> bf16 (inputs are finite)
  unsigned int u = __float_as_uint(f);
  u += 0x7fffu + ((u >> 16) & 1u);
  return (unsigned short)(u >> 16);
}

__device__ __forceinline__ void async16(const void* g, void* l) {
  // wave-level DMA: lane i's 16B from its own gaddr -> (uniform lds base) + i*16
  __builtin_amdgcn_global_load_lds(
      (const __attribute__((address_space(1))) unsigned int*)g,
      (__attribute__((address_space(3))) unsigned int*)l, 16, 0, 0);
}

// ---------------- k1: Q = query @ W1  (64x512 = 64 blocks x 256 thr) --------
__global__ void qk(const float* __restrict__ query, const float* __restrict__ W1,
                   float* __restrict__ Q) {
  __shared__ float qrow[512];
  const int b = blockIdx.x, t = threadIdx.x;
  qrow[t] = query[b * 512 + t];
  qrow[t + 256] = query[b * 512 + t + 256];
  __syncthreads();
  float a0 = 0.f, a1 = 0.f;
  for (int k = 0; k < 512; ++k) {
    const float q = qrow[k];
    const float* w = W1 + (size_t)k * 512;
    a0 += q * w[t];
    a1 += q * w[t + 256];
  }
  Q[b * 512 + t] = a0;
  Q[b * 512 + t + 256] = a1;
}

// ---------------- k2: Wt[u][d] = bf16(W2[d][u]) -----------------------------
__global__ void wt_k(const float* __restrict__ W2, unsigned short* __restrict__ Wt) {
  __shared__ float tile[32][33];
  const int k0 = blockIdx.x * 32, n0 = blockIdx.y * 32;
  const int tx = threadIdx.x, ty = threadIdx.y;  // 32 x 8
  for (int i = 0; i < 32; i += 8)
    tile[ty + i][tx] = W2[(size_t)(k0 + ty + i) * 512 + n0 + tx];
  __syncthreads();
  for (int i = 0; i < 32; i += 8)
    Wt[(size_t)(n0 + ty + i) * 512 + k0 + tx] = f2bf(tile[tx][ty + i]);
}

// ---------------- k3: fused scores ------------------------------------------
// Block: 64 rows (one M-tile, single b since 64 | 2048) x full U=512, K=512.
// 8 waves; wave w owns U-slice [w*64, w*64+64) as 4x4 tiles of 16x16x32 MFMA.
// LDS: A 64x512 bf16 (64KB) full-K; B piece 512n x 64k bf16 (64KB), 8 pieces.
// 16B chunks xor-swizzled: slot = kc ^ (row&7)  => 2-way bank access (free).
__global__ __launch_bounds__(512, 2) void scores_k(
    const float* __restrict__ values, const unsigned short* __restrict__ Wt,
    const float* __restrict__ Q, const float* __restrict__ V1,
    float* __restrict__ scores) {
  __shared__ __align__(16) unsigned short Ab[64 * 512];  // [m][512k], swizzled
  __shared__ __align__(16) unsigned short Bb[512 * 64];  // [n][64k],  swizzled
  __shared__ float sAcc[64];

  const int t = threadIdx.x;
  const int lane = t & 63;
  const int w = t >> 6;        // wave 0..7
  const int quad = lane >> 4;  // 0..3
  const int l15 = lane & 15;
  const int m0 = blockIdx.x * 64;
  const int b = m0 >> 11;  // /2048

  if (t < 64) sAcc[t] = 0.0f;

  // ---- stage A: 64 rows x 512 k, fp32 -> bf16, swizzled 16B chunks
  const float* Ag = values + (size_t)m0 * 512;
#pragma unroll
  for (int i = 0; i < 8; ++i) {
    const int c = i * 512 + t;  // chunk id: 64 rows x 64 chunks
    const int m = c >> 6;
    const int kc = c & 63;
    const float4* src = (const float4*)(Ag + (size_t)m * 512 + kc * 8);
    const float4 x = src[0], y = src[1];
    const unsigned int p0 = (unsigned int)f2bf(x.x) | ((unsigned int)f2bf(x.y) << 16);
    const unsigned int p1 = (unsigned int)f2bf(x.z) | ((unsigned int)f2bf(x.w) << 16);
    const unsigned int p2 = (unsigned int)f2bf(y.x) | ((unsigned int)f2bf(y.y) << 16);
    const unsigned int p3 = (unsigned int)f2bf(y.z) | ((unsigned int)f2bf(y.w) << 16);
    *(uint4*)&Ab[m * 512 + ((kc ^ (m & 7)) * 8)] = make_uint4(p0, p1, p2, p3);
  }

  f32x4 acc[4][4];
#pragma unroll
  for (int mt = 0; mt < 4; ++mt)
#pragma unroll
    for (int nt = 0; nt < 4; ++nt) acc[mt][nt] = (f32x4){0.f, 0.f, 0.f, 0.f};

  for (int piece = 0; piece < 8; ++piece) {
    __syncthreads();  // prev piece consumed (iter 0: orders A ds_writes too)
    // ---- stage B piece via global_load_lds: wave w covers n in [w*64,+64)
    // lane i -> lds (nb*64 + i*8 shorts): row n = nb+i/8, slot s = i&7;
    // slot s of row n must hold global chunk kc = s ^ (n&7).
#pragma unroll
    for (int j = 0; j < 8; ++j) {
      const int nb = w * 64 + j * 8;
      const int n = nb + (lane >> 3);
      const int kcc = (lane & 7) ^ (n & 7);
      const unsigned short* g = Wt + (size_t)n * 512 + piece * 64 + kcc * 8;
      async16(g, &Bb[nb * 64]);
    }
    __syncthreads();  // DMA drained (barrier drains vmcnt)

#pragma unroll
    for (int ksl = 0; ksl < 2; ++ksl) {  // two k-steps of 32 per piece
      bf16x8 af[4], bfr[4];
      const int kc = piece * 8 + ksl * 4 + quad;  // global A chunk index
      const int kcc = ksl * 4 + quad;             // piece-local B chunk index
#pragma unroll
      for (int mt = 0; mt < 4; ++mt) {
        const int m = mt * 16 + l15;
        af[mt] = *(const bf16x8*)&Ab[m * 512 + ((kc ^ (m & 7)) * 8)];
      }
#pragma unroll
      for (int nt = 0; nt < 4; ++nt) {
        const int n = w * 64 + nt * 16 + l15;
        bfr[nt] = *(const bf16x8*)&Bb[n * 64 + ((kcc ^ (n & 7)) * 8)];
      }
#pragma unroll
      for (int mt = 0; mt < 4; ++mt)
#pragma unroll
        for (int nt = 0; nt < 4; ++nt)
          acc[mt][nt] = __builtin_amdgcn_mfma_f32_16x16x32_bf16(af[mt], bfr[nt],
                                                                acc[mt][nt], 0, 0, 0);
    }
  }

  // ---- epilogue: part[m] += tanh(acc + Q[b,n]) * V1[n], reduce over n
  // C/D layout: col(n) = lane&15, row(m within tile) = quad*4 + r
  float part[4][4];
#pragma unroll
  for (int mt = 0; mt < 4; ++mt)
#pragma unroll
    for (int r = 0; r < 4; ++r) part[mt][r] = 0.f;

#pragma unroll
  for (int nt = 0; nt < 4; ++nt) {
    const int n = w * 64 + nt * 16 + l15;
    const float qv = Q[b * 512 + n];
    const float v1 = V1[n];
#pragma unroll
    for (int mt = 0; mt < 4; ++mt)
#pragma unroll
      for (int r = 0; r < 4; ++r) {
        const float x = acc[mt][nt][r] + qv;
        // tanh(x) = 1 - 2/(e^{2x}+1); e^{2x} = 2^(2x*log2 e). Saturates cleanly.
        const float e = fast_exp2(x * 2.8853900817779268f);
        const float th = 1.0f - 2.0f * fast_rcp(e + 1.0f);
        part[mt][r] += th * v1;
      }
  }
  // reduce over the 16 columns (lane bits 0..3), then across waves via LDS
#pragma unroll
  for (int mt = 0; mt < 4; ++mt)
#pragma unroll
    for (int r = 0; r < 4; ++r) {
      float v = part[mt][r];
      v += __shfl_xor(v, 1);
      v += __shfl_xor(v, 2);
      v += __shfl_xor(v, 4);
      v += __shfl_xor(v, 8);
      if (l15 == 0) atomicAdd(&sAcc[mt * 16 + quad * 4 + r], v);
    }
  __syncthreads();
  if (t < 64) scores[m0 + t] = sAcc[t];
}

// ---------------- k4: softmax over S (in place), one block per b ------------
__global__ void softmax_k(float* __restrict__ scores) {
  __shared__ float red[8];
  const int bq = blockIdx.x, t = threadIdx.x;  // 256 threads
  float* s = scores + (size_t)bq * 2048;
  float v[8];
  float mx = -3.0e38f;
#pragma unroll
  for (int i = 0; i < 8; ++i) {
    v[i] = s[t + i * 256];
    mx = fmaxf(mx, v[i]);
  }
#pragma unroll
  for (int o = 1; o < 64; o <<= 1) mx = fmaxf(mx, __shfl_xor(mx, o));
  if ((t & 63) == 0) red[t >> 6] = mx;
  __syncthreads();
  mx = fmaxf(fmaxf(red[0], red[1]), fmaxf(red[2], red[3]));
  float e[8];
  float sum = 0.f;
#pragma unroll
  for (int i = 0; i < 8; ++i) {
    e[i] = fast_exp2((v[i] - mx) * 1.4426950408889634f);
    sum += e[i];
  }
#pragma unroll
  for (int o = 1; o < 64; o <<= 1) sum += __shfl_xor(sum, o);
  if ((t & 63) == 0) red[4 + (t >> 6)] = sum;
  __syncthreads();
  const float inv = 1.0f / (red[4] + red[5] + red[6] + red[7]);
#pragma unroll
  for (int i = 0; i < 8; ++i) s[t + i * 256] = e[i] * inv;
}

// ---------------- k5: context = sum_s attn * values -------------------------
// grid 256: (b, d-chunk of 128); 1024 thr = 8 s-groups x 128 d-lanes
__global__ __launch_bounds__(1024) void ctx_k(const float* __restrict__ values,
                                              const float* __restrict__ attn,
                                              float* __restrict__ out) {
  __shared__ float red[1024];
  const int bid = blockIdx.x;
  const int b = bid >> 2, dc = bid & 3;
  const int t = threadIdx.x;
  const int d = dc * 128 + (t & 127);
  const int sg = t >> 7;  // 0..7
  const float* vb = values + (size_t)b * 2048 * 512;
  const float* ab = attn + (size_t)b * 2048;
  float acc = 0.f;
#pragma unroll 4
  for (int s = sg; s < 2048; s += 8) acc += ab[s] * vb[(size_t)s * 512 + d];
  red[t] = acc;
  __syncthreads();
  if (t < 128) {
    float r = 0.f;
#pragma unroll
    for (int i = 0; i < 8; ++i) r += red[t + i * 128];
    out[b * 512 + dc * 128 + t] = r;
  }
}

extern "C" void kernel_launch(void* const* d_in, const int* in_sizes, int n_in,
                              void* d_out, int out_size, void* d_ws, size_t ws_size,
                              hipStream_t stream) {
  const float* query = (const float*)d_in[0];   // (64, 512)
  const float* values = (const float*)d_in[1];  // (64, 2048, 512)
  const float* W1 = (const float*)d_in[2];      // (512, 512)
  const float* W2 = (const float*)d_in[3];      // (512, 512)
  const float* V1 = (const float*)d_in[4];      // (512, 1)
  float* out = (float*)d_out;                   // (64, 512)

  char* ws = (char*)d_ws;
  float* Qp = (float*)ws;                                // 131072 B
  unsigned short* Wtp = (unsigned short*)(ws + 131072);  // 524288 B
  float* Sp = (float*)(ws + 131072 + 524288);            // 524288 B

  qk<<<64, 256, 0, stream>>>(query, W1, Qp);
  wt_k<<<dim3(16, 16), dim3(32, 8), 0, stream>>>(W2, Wtp);
  scores_k<<<2048, 512, 0, stream>>>(values, Wtp, Qp, V1, Sp);
  softmax_k<<<64, 256, 0, stream>>>(Sp);
  ctx_k<<<256, 1024, 0, stream>>>(values, Sp, out);
}

// Round 2
// 528.598 us; speedup vs baseline: 1.0541x; 1.0541x over previous
//
#include <hip/hip_runtime.h>

// AdditiveAttention on MI355X (gfx950)
// B=64, S=2048, D=512, U=512. All inputs fp32; output fp32 (B,D).
//
// R2: scores_k restructured — B fragments load straight from L2-resident Wt
// (coalesced 16B/lane, one 64B line per 16 rows), no B LDS, no K-loop
// barriers. LDS 128.5KB -> 64.25KB => 2 blocks/CU. ctx_k: 512 blocks + atomics.

typedef __attribute__((ext_vector_type(8))) short bf16x8;
typedef __attribute__((ext_vector_type(4))) float f32x4;

#if __has_builtin(__builtin_amdgcn_exp2f)
__device__ __forceinline__ float fast_exp2(float x) { return __builtin_amdgcn_exp2f(x); }
#else
__device__ __forceinline__ float fast_exp2(float x) { return exp2f(x); }
#endif
#if __has_builtin(__builtin_amdgcn_rcpf)
__device__ __forceinline__ float fast_rcp(float x) { return __builtin_amdgcn_rcpf(x); }
#else
__device__ __forceinline__ float fast_rcp(float x) { return 1.0f / x; }
#endif

__device__ __forceinline__ unsigned short f2bf(float f) {
  unsigned int u = __float_as_uint(f);
  u += 0x7fffu + ((u >> 16) & 1u);
  return (unsigned short)(u >> 16);
}

// ---------------- k1: Q = query @ W1  (64x2 blocks x 256 thr) ---------------
__global__ void qk(const float* __restrict__ query, const float* __restrict__ W1,
                   float* __restrict__ Q) {
  __shared__ float qrow[512];
  const int b = blockIdx.x, half = blockIdx.y, t = threadIdx.x;
  qrow[t] = query[b * 512 + t];
  qrow[t + 256] = query[b * 512 + t + 256];
  __syncthreads();
  const int u = half * 256 + t;
  float acc = 0.f;
#pragma unroll 8
  for (int k = 0; k < 512; ++k) acc += qrow[k] * W1[(size_t)k * 512 + u];
  Q[b * 512 + u] = acc;
}

// ---------------- k2: Wt[u][d] = bf16(W2[d][u]) -----------------------------
__global__ void wt_k(const float* __restrict__ W2, unsigned short* __restrict__ Wt) {
  __shared__ float tile[32][33];
  const int k0 = blockIdx.x * 32, n0 = blockIdx.y * 32;
  const int tx = threadIdx.x, ty = threadIdx.y;  // 32 x 8
  for (int i = 0; i < 32; i += 8)
    tile[ty + i][tx] = W2[(size_t)(k0 + ty + i) * 512 + n0 + tx];
  __syncthreads();
  for (int i = 0; i < 32; i += 8)
    Wt[(size_t)(n0 + ty + i) * 512 + k0 + tx] = f2bf(tile[tx][ty + i]);
}

// ---------------- k3: fused scores ------------------------------------------
// Block: 64 rows x full U=512, K=512. 8 waves; wave w owns U-slice
// [w*64, w*64+64) as 4 n-tiles x 4 m-tiles of 16x16x32 bf16 MFMA.
// A (values rows) -> bf16 LDS full-K, xor-swizzled 16B chunks (64KB).
// B fragments: direct global loads from Wt (L2-resident, 512KB total).
// One barrier total; K-loop has no barriers.
__global__ __launch_bounds__(512, 4) void scores_k(
    const float* __restrict__ values, const unsigned short* __restrict__ Wt,
    const float* __restrict__ Q, const float* __restrict__ V1,
    float* __restrict__ scores) {
  __shared__ __align__(16) unsigned short Ab[64 * 512];  // [m][512k], swizzled
  __shared__ float sAcc[64];

  const int t = threadIdx.x;
  const int lane = t & 63;
  const int w = t >> 6;        // wave 0..7
  const int quad = lane >> 4;  // 0..3
  const int l15 = lane & 15;
  const int m0 = blockIdx.x * 64;
  const int b = m0 >> 11;  // /2048

  if (t < 64) sAcc[t] = 0.0f;

  // ---- stage A: 64 rows x 512 k, fp32 -> bf16, swizzled 16B chunks
  const float* Ag = values + (size_t)m0 * 512;
#pragma unroll
  for (int i = 0; i < 8; ++i) {
    const int c = i * 512 + t;  // chunk id: 64 rows x 64 chunks
    const int m = c >> 6;
    const int kc = c & 63;
    const float4* src = (const float4*)(Ag + (size_t)m * 512 + kc * 8);
    const float4 x = src[0], y = src[1];
    const unsigned int p0 = (unsigned int)f2bf(x.x) | ((unsigned int)f2bf(x.y) << 16);
    const unsigned int p1 = (unsigned int)f2bf(x.z) | ((unsigned int)f2bf(x.w) << 16);
    const unsigned int p2 = (unsigned int)f2bf(y.x) | ((unsigned int)f2bf(y.y) << 16);
    const unsigned int p3 = (unsigned int)f2bf(y.z) | ((unsigned int)f2bf(y.w) << 16);
    *(uint4*)&Ab[m * 512 + ((kc ^ (m & 7)) * 8)] = make_uint4(p0, p1, p2, p3);
  }
  __syncthreads();

  f32x4 acc[4][4];
#pragma unroll
  for (int mt = 0; mt < 4; ++mt)
#pragma unroll
    for (int nt = 0; nt < 4; ++nt) acc[mt][nt] = (f32x4){0.f, 0.f, 0.f, 0.f};

  // wave-invariant B base: row n = w*64 + nt*16 + l15, k-offset quad*8
  const unsigned short* Bg = Wt + (size_t)(w * 64 + l15) * 512 + quad * 8;
  const int sw = l15 & 7;  // A swizzle key (m&7 == l15&7)

#pragma unroll
  for (int ks = 0; ks < 16; ++ks) {  // 16 k-steps of 32
    bf16x8 bfr[4], af[4];
#pragma unroll
    for (int nt = 0; nt < 4; ++nt)
      bfr[nt] = *(const bf16x8*)(Bg + nt * (16 * 512) + ks * 32);
#pragma unroll
    for (int mt = 0; mt < 4; ++mt) {
      const int m = mt * 16 + l15;
      af[mt] = *(const bf16x8*)&Ab[m * 512 + (((ks * 4 + quad) ^ sw) * 8)];
    }
#pragma unroll
    for (int mt = 0; mt < 4; ++mt)
#pragma unroll
      for (int nt = 0; nt < 4; ++nt)
        acc[mt][nt] = __builtin_amdgcn_mfma_f32_16x16x32_bf16(af[mt], bfr[nt],
                                                              acc[mt][nt], 0, 0, 0);
  }

  // ---- epilogue: part[m] += tanh(acc + Q[b,n]) * V1[n], reduce over n
  // C/D layout: col(n) = lane&15, row(m within tile) = quad*4 + r
  float part[4][4];
#pragma unroll
  for (int mt = 0; mt < 4; ++mt)
#pragma unroll
    for (int r = 0; r < 4; ++r) part[mt][r] = 0.f;

#pragma unroll
  for (int nt = 0; nt < 4; ++nt) {
    const int n = w * 64 + nt * 16 + l15;
    const float qv = Q[b * 512 + n];
    const float v1 = V1[n];
#pragma unroll
    for (int mt = 0; mt < 4; ++mt)
#pragma unroll
      for (int r = 0; r < 4; ++r) {
        const float x = acc[mt][nt][r] + qv;
        const float e = fast_exp2(x * 2.8853900817779268f);  // e^{2x}
        const float th = 1.0f - 2.0f * fast_rcp(e + 1.0f);   // tanh(x)
        part[mt][r] += th * v1;
      }
  }
#pragma unroll
  for (int mt = 0; mt < 4; ++mt)
#pragma unroll
    for (int r = 0; r < 4; ++r) {
      float v = part[mt][r];
      v += __shfl_xor(v, 1);
      v += __shfl_xor(v, 2);
      v += __shfl_xor(v, 4);
      v += __shfl_xor(v, 8);
      if (l15 == 0) atomicAdd(&sAcc[mt * 16 + quad * 4 + r], v);
    }
  __syncthreads();
  if (t < 64) scores[m0 + t] = sAcc[t];
}

// ---------------- k4: softmax over S (in place) + zero out ------------------
__global__ void softmax_k(float* __restrict__ scores, float* __restrict__ out) {
  __shared__ float red[8];
  const int bq = blockIdx.x, t = threadIdx.x;  // 256 threads
  out[bq * 512 + t] = 0.f;  // zero-init for ctx_k atomics
  out[bq * 512 + 256 + t] = 0.f;
  float* s = scores + (size_t)bq * 2048;
  float v[8];
  float mx = -3.0e38f;
#pragma unroll
  for (int i = 0; i < 8; ++i) {
    v[i] = s[t + i * 256];
    mx = fmaxf(mx, v[i]);
  }
#pragma unroll
  for (int o = 1; o < 64; o <<= 1) mx = fmaxf(mx, __shfl_xor(mx, o));
  if ((t & 63) == 0) red[t >> 6] = mx;
  __syncthreads();
  mx = fmaxf(fmaxf(red[0], red[1]), fmaxf(red[2], red[3]));
  float e[8];
  float sum = 0.f;
#pragma unroll
  for (int i = 0; i < 8; ++i) {
    e[i] = fast_exp2((v[i] - mx) * 1.4426950408889634f);
    sum += e[i];
  }
#pragma unroll
  for (int o = 1; o < 64; o <<= 1) sum += __shfl_xor(sum, o);
  if ((t & 63) == 0) red[4 + (t >> 6)] = sum;
  __syncthreads();
  const float inv = 1.0f / (red[4] + red[5] + red[6] + red[7]);
#pragma unroll
  for (int i = 0; i < 8; ++i) s[t + i * 256] = e[i] * inv;
}

// ---------------- k5: context = sum_s attn * values -------------------------
// grid 512: (b, s-chunk of 256); 512 thr = one d each; atomicAdd into out.
__global__ __launch_bounds__(512) void ctx_k(const float* __restrict__ values,
                                             const float* __restrict__ attn,
                                             float* __restrict__ out) {
  const int bid = blockIdx.x;
  const int b = bid >> 3, sc = bid & 7;
  const int t = threadIdx.x;
  const float* vb = values + (size_t)b * 2048 * 512 + (size_t)sc * 256 * 512;
  const float* ab = attn + (size_t)b * 2048 + sc * 256;
  float acc = 0.f;
#pragma unroll 8
  for (int s = 0; s < 256; ++s) acc += ab[s] * vb[(size_t)s * 512 + t];
  atomicAdd(&out[b * 512 + t], acc);
}

extern "C" void kernel_launch(void* const* d_in, const int* in_sizes, int n_in,
                              void* d_out, int out_size, void* d_ws, size_t ws_size,
                              hipStream_t stream) {
  const float* query = (const float*)d_in[0];   // (64, 512)
  const float* values = (const float*)d_in[1];  // (64, 2048, 512)
  const float* W1 = (const float*)d_in[2];      // (512, 512)
  const float* W2 = (const float*)d_in[3];      // (512, 512)
  const float* V1 = (const float*)d_in[4];      // (512, 1)
  float* out = (float*)d_out;                   // (64, 512)

  char* ws = (char*)d_ws;
  float* Qp = (float*)ws;                                // 131072 B
  unsigned short* Wtp = (unsigned short*)(ws + 131072);  // 524288 B
  float* Sp = (float*)(ws + 131072 + 524288);            // 524288 B

  qk<<<dim3(64, 2), 256, 0, stream>>>(query, W1, Qp);
  wt_k<<<dim3(16, 16), dim3(32, 8), 0, stream>>>(W2, Wtp);
  scores_k<<<2048, 512, 0, stream>>>(values, Wtp, Qp, V1, Sp);
  softmax_k<<<64, 256, 0, stream>>>(Sp, out);
  ctx_k<<<512, 512, 0, stream>>>(values, Sp, out);
}

// Round 3
// 498.865 us; speedup vs baseline: 1.1169x; 1.0596x over previous
//
#include <hip/hip_runtime.h>

// AdditiveAttention on MI355X (gfx950)
// B=64, S=2048, D=512, U=512. All inputs fp32; output fp32 (B,D).
//
// R3: Wt stored in MFMA-fragment order => each B load is one contiguous 1KB
// wave transaction (was 16 x 64B scatter). softmax fused into ctx_k; out
// zero-init fused into wt_k. 4 kernels total.

typedef __attribute__((ext_vector_type(8))) short bf16x8;
typedef __attribute__((ext_vector_type(4))) float f32x4;

#if __has_builtin(__builtin_amdgcn_exp2f)
__device__ __forceinline__ float fast_exp2(float x) { return __builtin_amdgcn_exp2f(x); }
#else
__device__ __forceinline__ float fast_exp2(float x) { return exp2f(x); }
#endif
#if __has_builtin(__builtin_amdgcn_rcpf)
__device__ __forceinline__ float fast_rcp(float x) { return __builtin_amdgcn_rcpf(x); }
#else
__device__ __forceinline__ float fast_rcp(float x) { return 1.0f / x; }
#endif

__device__ __forceinline__ unsigned short f2bf(float f) {
  unsigned int u = __float_as_uint(f);
  u += 0x7fffu + ((u >> 16) & 1u);
  return (unsigned short)(u >> 16);
}

// ---------------- k1: Q = query @ W1  (64x2 blocks x 256 thr) ---------------
__global__ void qk(const float* __restrict__ query, const float* __restrict__ W1,
                   float* __restrict__ Q) {
  __shared__ float qrow[512];
  const int b = blockIdx.x, half = blockIdx.y, t = threadIdx.x;
  qrow[t] = query[b * 512 + t];
  qrow[t + 256] = query[b * 512 + t + 256];
  __syncthreads();
  const int u = half * 256 + t;
  float acc = 0.f;
#pragma unroll 8
  for (int k = 0; k < 512; ++k) acc += qrow[k] * W1[(size_t)k * 512 + u];
  Q[b * 512 + u] = acc;
}

// ---------------- k2: Wtf = fragment-ordered bf16(W2^T); also zero out ------
// Wtf[((ntile*16+ks)*64 + quad*16 + l15)*8 + j] = bf16(W2[ks*32+quad*8+j][ntile*16+l15])
// One thread = one (group,lane): writes 16B contiguous; 32768 threads total.
__global__ void wt_k(const float* __restrict__ W2, unsigned short* __restrict__ Wtf,
                     float* __restrict__ out0) {
  const int gid = blockIdx.x * 256 + threadIdx.x;  // 0..32767
  out0[gid] = 0.f;                                 // zero d_out for ctx atomics
  const int lane = gid & 63;
  const int g = gid >> 6;  // ntile*16 + ks
  const int ks = g & 15, ntile = g >> 4;
  const int l15 = lane & 15, quad = lane >> 4;
  const int n = ntile * 16 + l15;
  const int k0 = ks * 32 + quad * 8;
  unsigned int p[4];
#pragma unroll
  for (int jj = 0; jj < 4; ++jj) {
    const float a = W2[(size_t)(k0 + 2 * jj) * 512 + n];
    const float b = W2[(size_t)(k0 + 2 * jj + 1) * 512 + n];
    p[jj] = (unsigned int)f2bf(a) | ((unsigned int)f2bf(b) << 16);
  }
  *(uint4*)&Wtf[(size_t)gid * 8] = make_uint4(p[0], p[1], p[2], p[3]);
}

// ---------------- k3: fused scores ------------------------------------------
// Block: 64 rows x full U=512, K=512. 8 waves; wave w owns n-tiles w*4..w*4+3.
// A (values rows) -> bf16 LDS full-K, xor-swizzled 16B chunks (64KB).
// B fragments: contiguous 1KB wave loads from fragment-ordered Wtf (L2-res).
__global__ __launch_bounds__(512, 4) void scores_k(
    const float* __restrict__ values, const unsigned short* __restrict__ Wtf,
    const float* __restrict__ Q, const float* __restrict__ V1,
    float* __restrict__ scores) {
  __shared__ __align__(16) unsigned short Ab[64 * 512];  // [m][512k], swizzled
  __shared__ float sAcc[64];

  const int t = threadIdx.x;
  const int lane = t & 63;
  const int w = t >> 6;        // wave 0..7
  const int quad = lane >> 4;  // 0..3
  const int l15 = lane & 15;
  const int m0 = blockIdx.x * 64;
  const int b = m0 >> 11;  // /2048

  if (t < 64) sAcc[t] = 0.0f;

  // ---- stage A: 64 rows x 512 k, fp32 -> bf16, swizzled 16B chunks
  const float* Ag = values + (size_t)m0 * 512;
#pragma unroll
  for (int i = 0; i < 8; ++i) {
    const int c = i * 512 + t;  // chunk id: 64 rows x 64 chunks
    const int m = c >> 6;
    const int kc = c & 63;
    const float4* src = (const float4*)(Ag + (size_t)m * 512 + kc * 8);
    const float4 x = src[0], y = src[1];
    const unsigned int p0 = (unsigned int)f2bf(x.x) | ((unsigned int)f2bf(x.y) << 16);
    const unsigned int p1 = (unsigned int)f2bf(x.z) | ((unsigned int)f2bf(x.w) << 16);
    const unsigned int p2 = (unsigned int)f2bf(y.x) | ((unsigned int)f2bf(y.y) << 16);
    const unsigned int p3 = (unsigned int)f2bf(y.z) | ((unsigned int)f2bf(y.w) << 16);
    *(uint4*)&Ab[m * 512 + ((kc ^ (m & 7)) * 8)] = make_uint4(p0, p1, p2, p3);
  }
  __syncthreads();

  f32x4 acc[4][4];
#pragma unroll
  for (int mt = 0; mt < 4; ++mt)
#pragma unroll
    for (int nt = 0; nt < 4; ++nt) acc[mt][nt] = (f32x4){0.f, 0.f, 0.f, 0.f};

  const unsigned short* Bg = Wtf + (size_t)lane * 8;  // + ((ntile*16+ks)*512)
  const int sw = l15 & 7;  // A swizzle key (m&7 == l15&7)

#pragma unroll
  for (int ks = 0; ks < 16; ++ks) {  // 16 k-steps of 32
    bf16x8 bfr[4], af[4];
#pragma unroll
    for (int nt = 0; nt < 4; ++nt)
      bfr[nt] = *(const bf16x8*)(Bg + (size_t)((w * 4 + nt) * 16 + ks) * 512);
#pragma unroll
    for (int mt = 0; mt < 4; ++mt) {
      const int m = mt * 16 + l15;
      af[mt] = *(const bf16x8*)&Ab[m * 512 + (((ks * 4 + quad) ^ sw) * 8)];
    }
#pragma unroll
    for (int mt = 0; mt < 4; ++mt)
#pragma unroll
      for (int nt = 0; nt < 4; ++nt)
        acc[mt][nt] = __builtin_amdgcn_mfma_f32_16x16x32_bf16(af[mt], bfr[nt],
                                                              acc[mt][nt], 0, 0, 0);
  }

  // ---- epilogue: part[m] += tanh(acc + Q[b,n]) * V1[n], reduce over n
  // C/D layout: col(n) = lane&15, row(m within tile) = quad*4 + r
  float part[4][4];
#pragma unroll
  for (int mt = 0; mt < 4; ++mt)
#pragma unroll
    for (int r = 0; r < 4; ++r) part[mt][r] = 0.f;

#pragma unroll
  for (int nt = 0; nt < 4; ++nt) {
    const int n = w * 64 + nt * 16 + l15;
    const float qv = Q[b * 512 + n];
    const float v1 = V1[n];
#pragma unroll
    for (int mt = 0; mt < 4; ++mt)
#pragma unroll
      for (int r = 0; r < 4; ++r) {
        const float x = acc[mt][nt][r] + qv;
        const float e = fast_exp2(x * 2.8853900817779268f);  // e^{2x}
        const float th = 1.0f - 2.0f * fast_rcp(e + 1.0f);   // tanh(x)
        part[mt][r] += th * v1;
      }
  }
#pragma unroll
  for (int mt = 0; mt < 4; ++mt)
#pragma unroll
    for (int r = 0; r < 4; ++r) {
      float v = part[mt][r];
      v += __shfl_xor(v, 1);
      v += __shfl_xor(v, 2);
      v += __shfl_xor(v, 4);
      v += __shfl_xor(v, 8);
      if (l15 == 0) atomicAdd(&sAcc[mt * 16 + quad * 4 + r], v);
    }
  __syncthreads();
  if (t < 64) scores[m0 + t] = sAcc[t];
}

// ---------------- k4: context with fused softmax ----------------------------
// grid 512: (b, s-chunk of 256); 512 thr. Each block recomputes softmax stats
// over all 2048 raw scores of its b (8KB read, trivial), then accumulates its
// 256-s chunk into out via atomicAdd (out zeroed by wt_k).
__global__ __launch_bounds__(512) void ctx_k(const float* __restrict__ values,
                                             const float* __restrict__ scores,
                                             float* __restrict__ out) {
  __shared__ float red[16];
  __shared__ float wsc[256];
  const int bid = blockIdx.x;
  const int b = bid >> 3, sc = bid & 7;
  const int t = threadIdx.x;
  const float* sb = scores + (size_t)b * 2048;
  const float v0 = sb[t], v1 = sb[t + 512], v2 = sb[t + 1024], v3 = sb[t + 1536];
  float mx = fmaxf(fmaxf(v0, v1), fmaxf(v2, v3));
#pragma unroll
  for (int o = 1; o < 64; o <<= 1) mx = fmaxf(mx, __shfl_xor(mx, o));
  if ((t & 63) == 0) red[t >> 6] = mx;
  __syncthreads();
  mx = fmaxf(fmaxf(fmaxf(red[0], red[1]), fmaxf(red[2], red[3])),
             fmaxf(fmaxf(red[4], red[5]), fmaxf(red[6], red[7])));
  const float L2E = 1.4426950408889634f;
  float sum = fast_exp2((v0 - mx) * L2E) + fast_exp2((v1 - mx) * L2E) +
              fast_exp2((v2 - mx) * L2E) + fast_exp2((v3 - mx) * L2E);
#pragma unroll
  for (int o = 1; o < 64; o <<= 1) sum += __shfl_xor(sum, o);
  if ((t & 63) == 0) red[8 + (t >> 6)] = sum;
  __syncthreads();
  sum = (red[8] + red[9]) + (red[10] + red[11]) + (red[12] + red[13]) +
        (red[14] + red[15]);
  const float inv = 1.0f / sum;
  if (t < 256) wsc[t] = fast_exp2((sb[sc * 256 + t] - mx) * L2E) * inv;
  __syncthreads();
  const float* vb = values + ((size_t)b * 2048 + sc * 256) * 512;
  float acc = 0.f;
#pragma unroll 8
  for (int s = 0; s < 256; ++s) acc += wsc[s] * vb[(size_t)s * 512 + t];
  atomicAdd(&out[b * 512 + t], acc);
}

extern "C" void kernel_launch(void* const* d_in, const int* in_sizes, int n_in,
                              void* d_out, int out_size, void* d_ws, size_t ws_size,
                              hipStream_t stream) {
  const float* query = (const float*)d_in[0];   // (64, 512)
  const float* values = (const float*)d_in[1];  // (64, 2048, 512)
  const float* W1 = (const float*)d_in[2];      // (512, 512)
  const float* W2 = (const float*)d_in[3];      // (512, 512)
  const float* V1 = (const float*)d_in[4];      // (512, 1)
  float* out = (float*)d_out;                   // (64, 512)

  char* ws = (char*)d_ws;
  float* Qp = (float*)ws;                                // 131072 B
  unsigned short* Wtp = (unsigned short*)(ws + 131072);  // 524288 B
  float* Sp = (float*)(ws + 131072 + 524288);            // 524288 B

  qk<<<dim3(64, 2), 256, 0, stream>>>(query, W1, Qp);
  wt_k<<<128, 256, 0, stream>>>(W2, Wtp, out);
  scores_k<<<2048, 512, 0, stream>>>(values, Wtp, Qp, V1, Sp);
  ctx_k<<<512, 512, 0, stream>>>(values, Sp, out);
}